// Round 1
// baseline (57.683 us; speedup 1.0000x reference)
//
#include <hip/hip_runtime.h>

// Block-factorized depthwise 7x7 conv, per-(n,c,8x8-block) filters.
// feat: [N=2, C=128, H=256, W=256] f32 (NCHW)
// filters_lr: [N, C*49, 32, 32] f32 ; weight[n,hb,wb,c,t] = filt[n, c*49+t, hb, wb]
// out[n,c,h,w] = sum_t feat[n,c,h+dh-3,w+dw-3] * weight[n,h/8,w/8,c,t], t=dh*7+dw

#define N_   2
#define C_   128
#define H_   256
#define W_   256
#define K_   7
#define K2   49
#define M_   8
#define HB   32
#define WB   32
#define PAD  3
#define ROWS 14          // M_ + K_ - 1 input rows per tile
#define LDW  264         // LDS row stride in floats (262 used, +2 -> 16B aligned rows)

__global__ __launch_bounds__(256)
void block_fac_kernel(const float* __restrict__ feat,
                      const float* __restrict__ filt,
                      float* __restrict__ out) {
    __shared__ float s_in[ROWS * LDW];   // 14*264*4 = 14784 B
    __shared__ float s_w[WB * K2];       // 32*49*4  =  6272 B

    const int bid = blockIdx.x;          // n*C*HB + c*HB + hb
    const int hb  = bid & (HB - 1);
    const int c   = (bid >> 5) & (C_ - 1);
    const int n   = bid >> 12;
    const int tid = threadIdx.x;

    // ---- stage weights: s_w[wb*49 + t] = filt[n, c*49+t, hb, wb]
    const float* wbase = filt + ((size_t)(n * C_ + c) * K2) * (HB * WB) + hb * WB;
    for (int idx = tid; idx < WB * K2; idx += 256) {
        int t  = idx >> 5;   // 0..48
        int wb = idx & 31;
        s_w[wb * K2 + t] = wbase[(size_t)t * (HB * WB) + wb];
    }

    // ---- zero the 3-col left/right pads
    if (tid < ROWS * 6) {
        int r = tid / 6, j = tid % 6;
        int p = (j < 3) ? j : (W_ + PAD + (j - 3));   // 0,1,2, 259,260,261
        s_in[r * LDW + p] = 0.f;
    }

    // ---- stage input rows hb*8-3 .. hb*8+10 (zero outside [0,H))
    const int h0 = hb * M_ - PAD;
    const float* fbase = feat + (size_t)(n * C_ + c) * (H_ * W_);
    for (int idx = tid; idx < ROWS * (W_ / 4); idx += 256) {   // 896 float4s
        int r  = idx >> 6;         // 0..13
        int c4 = (idx & 63) * 4;   // 0..252
        int gr = h0 + r;
        float4 v = make_float4(0.f, 0.f, 0.f, 0.f);
        if (gr >= 0 && gr < H_)
            v = *(const float4*)(fbase + (size_t)gr * W_ + c4);
        float* d = &s_in[r * LDW + PAD + c4];
        d[0] = v.x; d[1] = v.y; d[2] = v.z; d[3] = v.w;
    }
    __syncthreads();

    // ---- per-thread: 2 output rows x 4 cols
    const int lane = tid & 63;
    const int c0   = lane * 4;          // output col base (0..252)
    const int r0   = (tid >> 6) * 2;    // output row base within block (0,2,4,6)
    const int wb   = c0 >> 3;           // weight block col

    float wreg[K2];
    #pragma unroll
    for (int t = 0; t < K2; ++t) wreg[t] = s_w[wb * K2 + t];

    float acc0[4] = {0.f, 0.f, 0.f, 0.f};
    float acc1[4] = {0.f, 0.f, 0.f, 0.f};

    #pragma unroll
    for (int ri = 0; ri < 8; ++ri) {            // lds input row r0+ri
        const float* rp = &s_in[(r0 + ri) * LDW + c0];
        float4 a  = *(const float4*)(rp);
        float4 b  = *(const float4*)(rp + 4);
        float2 cc = *(const float2*)(rp + 8);
        float win[10] = {a.x, a.y, a.z, a.w, b.x, b.y, b.z, b.w, cc.x, cc.y};
        if (ri < 7) {                           // out row r0, dh = ri
            #pragma unroll
            for (int dw = 0; dw < 7; ++dw) {
                float wv = wreg[ri * 7 + dw];
                #pragma unroll
                for (int i = 0; i < 4; ++i) acc0[i] += win[dw + i] * wv;
            }
        }
        if (ri >= 1) {                          // out row r0+1, dh = ri-1
            #pragma unroll
            for (int dw = 0; dw < 7; ++dw) {
                float wv = wreg[(ri - 1) * 7 + dw];
                #pragma unroll
                for (int i = 0; i < 4; ++i) acc1[i] += win[dw + i] * wv;
            }
        }
    }

    float* obase = out + ((size_t)(n * C_ + c) * H_ + hb * M_ + r0) * W_ + c0;
    *(float4*)(obase)      = make_float4(acc0[0], acc0[1], acc0[2], acc0[3]);
    *(float4*)(obase + W_) = make_float4(acc1[0], acc1[1], acc1[2], acc1[3]);
}

extern "C" void kernel_launch(void* const* d_in, const int* in_sizes, int n_in,
                              void* d_out, int out_size, void* d_ws, size_t ws_size,
                              hipStream_t stream) {
    const float* feat = (const float*)d_in[0];
    const float* filt = (const float*)d_in[1];
    float* out = (float*)d_out;
    dim3 grid(N_ * C_ * HB);
    dim3 block(256);
    hipLaunchKernelGGL(block_fac_kernel, grid, block, 0, stream, feat, filt, out);
}